// Round 8
// baseline (2066.520 us; speedup 1.0000x reference)
//
#include <hip/hip_runtime.h>
#include <cstddef>

#define B_   8
#define N_   8192
#define M_   2048
#define K_   32
#define DIN_ 13

typedef _Float16 f16x8 __attribute__((ext_vector_type(8)));
typedef float    f32x4 __attribute__((ext_vector_type(4)));

// DPP-assisted reduce steps. Invalid source lanes yield identity. VALU-only.
template <int CTRL>
__device__ __forceinline__ float dppmax(float v) {
  int o = __builtin_amdgcn_update_dpp(
      (int)0xff800000, __float_as_int(v), CTRL, 0xF, 0xF, false);  // -inf
  return fmaxf(v, __int_as_float(o));
}
template <int CTRL>
__device__ __forceinline__ unsigned dppminu(unsigned v) {
  unsigned o = (unsigned)__builtin_amdgcn_update_dpp(
      (int)0xFFFFFFFF, (int)v, CTRL, 0xF, 0xF, false);  // u32 max = identity
  return v < o ? v : o;
}
template <int CTRL>
__device__ __forceinline__ unsigned dppmaxu(unsigned v) {
  unsigned o = (unsigned)__builtin_amdgcn_update_dpp(
      0, (int)v, CTRL, 0xF, 0xF, false);                // 0 = identity
  return v > o ? v : o;
}
__device__ __forceinline__ float wave_reduce_max(float v) {
  v = dppmax<0x111>(v); v = dppmax<0x112>(v); v = dppmax<0x114>(v);
  v = dppmax<0x118>(v); v = dppmax<0x142>(v); v = dppmax<0x143>(v);
  return __int_as_float(__builtin_amdgcn_readlane(__float_as_int(v), 63));
}
__device__ __forceinline__ unsigned wave_reduce_min_u32(unsigned v) {
  v = dppminu<0x111>(v); v = dppminu<0x112>(v); v = dppminu<0x114>(v);
  v = dppminu<0x118>(v); v = dppminu<0x142>(v); v = dppminu<0x143>(v);
  return (unsigned)__builtin_amdgcn_readlane((int)v, 63);
}
// Reduce 16 slot-values replicated per row (lane holds slot lane&15):
// 4 row_shr steps -> lane 63 holds max of all 16.
__device__ __forceinline__ unsigned row16_reduce_maxu(unsigned v) {
  v = dppmaxu<0x111>(v); v = dppmaxu<0x112>(v);
  v = dppmaxu<0x114>(v); v = dppmaxu<0x118>(v);
  return (unsigned)__builtin_amdgcn_readlane((int)v, 63);
}

// ---------------------------------------------------------------------------
// Kernel 1 v6: FPS, 1024 thr / 16 waves / 8 pts-lane (r4 granularity) +
// persistent double-buffered per-wave slots carrying {key, x, y, z}.
// r6 A/B showed: no-atomic DPP reduce cut latency but its u64 compare-select
// + post-reduce px_l[] broadcast reads cost more VALU than the atomic chain
// saved. v6 strips both: (a) owner lane writes candidate COORDS into the
// slot (exact register copies of px_l[cmin]) so the winner's coords come
// from readlane — no dependent px_l read, no index materialization;
// (b) two-phase 32-bit v_max_u32-DPP reduce (dist bits, then masked ~idx)
// replaces the u64 compare-select chain.
// !! r7 LESSON preserved: distance expression for PROCESSED points is
//    bit-identical (subtract-form, contract(off), jnp sum order). Sort only
//    permutes ownership. Tie-break: max dist bits, then max ~idx == min
//    orig idx. Selected point's owner wave always processes next iter
//    (LB=0 < ltm) -> no stale re-selection. Validated bit-exact r2/r4/r6.
// ---------------------------------------------------------------------------
__global__ __launch_bounds__(1024, 4) void fps_kernel(
    const float* __restrict__ pos,     // [B, N, 3]
    float* __restrict__ pos_s,         // [B, M, 3]
    float* __restrict__ batch_s)       // [B, M]
{
  const int b    = blockIdx.x;
  const int t    = threadIdx.x;
  const int lane = t & 63;
  const int wid  = t >> 6;             // 0..15
  const float* p = pos + (size_t)b * N_ * 3;

  __shared__ float px_l[N_], py_l[N_], pz_l[N_];   // 96 KB, ORIGINAL order
  __shared__ int   r2o[N_];                        // 32 KB, rank -> orig
  __shared__ int   vbase[512];
  __shared__ int   vcur[512];
  __shared__ int   wsum[8];
  __shared__ unsigned long long wkeyA[2][16];      // per-wave candidate key
  __shared__ float wcx[2][16], wcy[2][16], wcz[2][16];   // candidate coords

  for (int mm = t; mm < M_; mm += 1024)
    batch_s[b * M_ + mm] = (float)b;
  if (t < 512) vcur[t] = 0;
  __syncthreads();

  // --- load points + 512-bin Morton histogram (3 bits/axis) ---
  int vid[8];
#pragma unroll
  for (int i = 0; i < 8; ++i) {
    int j = t + 1024 * i;
    float x = p[j * 3 + 0], y = p[j * 3 + 1], z = p[j * 3 + 2];
    px_l[j] = x; py_l[j] = y; pz_l[j] = z;
    int ix = (int)(x * 8.f); ix = ix < 0 ? 0 : (ix > 7 ? 7 : ix);
    int iy = (int)(y * 8.f); iy = iy < 0 ? 0 : (iy > 7 ? 7 : iy);
    int iz = (int)(z * 8.f); iz = iz < 0 ? 0 : (iz > 7 ? 7 : iz);
    int v = (ix & 1) | ((iy & 1) << 1) | ((iz & 1) << 2) |
            (((ix >> 1) & 1) << 3) | (((iy >> 1) & 1) << 4) |
            (((iz >> 1) & 1) << 5) |
            ((ix >> 2) << 6) | ((iy >> 2) << 7) | ((iz >> 2) << 8);
    vid[i] = v;
    atomicAdd(&vcur[v], 1);
  }
  __syncthreads();

  // --- exclusive prefix over 512 bins (waves 0-7 scan, wave 0 combines) ---
  int h = 0, sc = 0;
  if (t < 512) {
    h = vcur[t]; sc = h;
#pragma unroll
    for (int d = 1; d < 64; d <<= 1) {
      int o = __shfl_up(sc, d);
      if (lane >= d) sc += o;
    }
    if (lane == 63) wsum[wid] = sc;
  }
  __syncthreads();
  if (t < 8) {
    int v = wsum[t]; int inc = v;
#pragma unroll
    for (int d = 1; d < 8; d <<= 1) {
      int o = __shfl_up(inc, d);
      if (t >= d) inc += o;
    }
    wsum[t] = inc - v;   // exclusive wave offset
  }
  __syncthreads();
  if (t < 512) { vbase[t] = sc - h + wsum[t >> 6]; vcur[t] = 0; }
  __syncthreads();

  // --- scatter: rank per point (within-voxel order nondeterministic; only
  //     affects ownership, never computed values) ---
#pragma unroll
  for (int i = 0; i < 8; ++i) {
    int j = t + 1024 * i;
    int r = vbase[vid[i]] + atomicAdd(&vcur[vid[i]], 1);
    r2o[r] = j;
  }
  __syncthreads();

  // --- gather: thread t owns ranks [8t,8t+8) (spatially tight) ---
  float px[8], py[8], pz[8], mind[8]; int oi[8];
#pragma unroll
  for (int i = 0; i < 8; ++i) {
    int o = r2o[t * 8 + i];
    oi[i] = o;
    px[i] = px_l[o]; py[i] = py_l[o]; pz[i] = pz_l[o];
    mind[i] = 1e10f;
  }
#pragma unroll
  for (int i = 0; i < 8; ++i) {
    asm volatile("" : "+v"(px[i]), "+v"(py[i]), "+v"(pz[i]));
  }

  // --- per-LANE bbox of the 8 owned points ---
  float bxmin = px[0], bxmax = px[0], bymin = py[0], bymax = py[0],
        bzmin = pz[0], bzmax = pz[0];
#pragma unroll
  for (int i = 1; i < 8; ++i) {
    bxmin = fminf(bxmin, px[i]); bxmax = fmaxf(bxmax, px[i]);
    bymin = fminf(bymin, py[i]); bymax = fmaxf(bymax, py[i]);
    bzmin = fminf(bzmin, pz[i]); bzmax = fmaxf(bzmax, pz[i]);
  }

  float lx = px_l[0], ly = py_l[0], lz = pz_l[0];
  if (t == 0) {
    pos_s[(size_t)b * M_ * 3 + 0] = lx;
    pos_s[(size_t)b * M_ * 3 + 1] = ly;
    pos_s[(size_t)b * M_ * 3 + 2] = lz;
  }

  float ltm = 1e10f;                  // max of MY 8 minds (exact, per-lane)
  unsigned long long ckey = 0;        // cached wave key (uniform value)
  bool  own = false;                  // THIS lane owns the wave's candidate
  float cox = 0.f, coy = 0.f, coz = 0.f;   // owner's candidate coords

  for (int s = 1; s < M_; ++s) {
    // per-lane conservative LB on fp-distance^2 from new center to owned pts
    float cx = fmaxf(fmaxf(bxmin - lx, lx - bxmax), 0.f);
    float cy = fmaxf(fmaxf(bymin - ly, ly - bymax), 0.f);
    float cz = fmaxf(fmaxf(bzmin - lz, lz - bzmax), 0.f);
    float LB = (cx * cx + cy * cy) + cz * cz;
    bool lp = (LB * 0.999999f < ltm);          // lane might change
    if (__ballot(lp) != 0ull) {                // wave-uniform branch
      float tmax;
      {
#pragma clang fp contract(off)
#pragma unroll
        for (int i = 0; i < 8; ++i) {
          float dx = px[i] - lx, dy = py[i] - ly, dz = pz[i] - lz;
          float d  = (dx * dx + dy * dy) + dz * dz;   // EXACT: jnp order, no fma
          mind[i]  = fminf(mind[i], d);
        }
        float m0 = fmaxf(mind[0], mind[1]), m1 = fmaxf(mind[2], mind[3]);
        float m2 = fmaxf(mind[4], mind[5]), m3 = fmaxf(mind[6], mind[7]);
        tmax = fmaxf(fmaxf(m0, m1), fmaxf(m2, m3));
      }
      ltm = tmax;
      const float wm = wave_reduce_max(tmax);
      unsigned cc = 0xFFFFFFFFu;   // smallest orig index among my ties
#pragma unroll
      for (int i = 0; i < 8; ++i) {
        unsigned cand = (mind[i] == wm) ? (unsigned)oi[i] : 0xFFFFFFFFu;
        cc = cc < cand ? cc : cand;
      }
      unsigned cmin = wave_reduce_min_u32(cc);
      ckey = ((unsigned long long)__float_as_uint(wm) << 32) |
             (unsigned long long)(0xFFFFFFFFu - cmin);
      // owner lane: holds point cmin -> exact register copy of its coords
      own = false;
#pragma unroll
      for (int i = 0; i < 8; ++i) {
        if ((unsigned)oi[i] == cmin) {
          own = true; cox = px[i]; coy = py[i]; coz = pz[i];
        }
      }
    }
    // persistent slot write (cached or fresh), no atomics, no reset
    if (lane == 0) wkeyA[s & 1][wid] = ckey;
    if (own) { wcx[s & 1][wid] = cox; wcy[s & 1][wid] = coy;
               wcz[s & 1][wid] = coz; }
    __syncthreads();                               // the ONE barrier
    // lane l holds slot l&15 (4x replicated, broadcast-free)
    const int slot = lane & 15;
    unsigned long long kk = wkeyA[s & 1][slot];
    float rx = wcx[s & 1][slot];
    float ry = wcy[s & 1][slot];
    float rz = wcz[s & 1][slot];
    unsigned khi = (unsigned)(kk >> 32), klo = (unsigned)kk;
    // two-phase 32-bit winner reduce
    const unsigned khi_max = row16_reduce_maxu(khi);
    unsigned klo2 = (khi == khi_max) ? klo : 0u;
    const unsigned klo_max = row16_reduce_maxu(klo2);
    // winner lane -> coords via readlane (uniform)
    unsigned long long wmk = __ballot(khi == khi_max && klo == klo_max);
    const int L = (int)(__ffsll((long long)wmk) - 1);
    lx = __int_as_float(__builtin_amdgcn_readlane(__float_as_int(rx), L));
    ly = __int_as_float(__builtin_amdgcn_readlane(__float_as_int(ry), L));
    lz = __int_as_float(__builtin_amdgcn_readlane(__float_as_int(rz), L));
    if (t == 0) {
      size_t o2 = ((size_t)b * M_ + s) * 3;
      pos_s[o2 + 0] = lx; pos_s[o2 + 1] = ly; pos_s[o2 + 2] = lz;
    }
  }
}

// ---------------------------------------------------------------------------
// Prep: transpose + fp16-convert weights into workspace (once per launch).
// w1t [64 n][16 k] = W1^T ; w2t [128 n][64 k] = W2^T.
// ---------------------------------------------------------------------------
__global__ __launch_bounds__(256) void prep_kernel(
    const float* __restrict__ W1, const float* __restrict__ W2,
    _Float16* __restrict__ w1t, _Float16* __restrict__ w2t)
{
  int t = blockIdx.x * 256 + threadIdx.x;
  if (t < 8192) {
    int n = t >> 6, k = t & 63;
    w2t[t] = (_Float16)W2[k * 128 + n];
  }
  int u = t - 8192;
  if (u >= 0 && u < 1024) {
    int n = u >> 4, k = u & 15;
    w1t[u] = (_Float16)W1[k * 64 + n];
  }
}

// ---------------------------------------------------------------------------
// Kernel 2 v2: ball query (exact fp32) + gather + MFMA fp16 MLP + masked max.
// UNCHANGED (control) — see round-1 comments.
// ---------------------------------------------------------------------------
__global__ __launch_bounds__(64) void sa_kernel(
    const float* __restrict__ x,       // [B, N, 13]
    const float* __restrict__ pos,     // [B, N, 3]
    const float* __restrict__ b1,      // [64]
    const float* __restrict__ b2,      // [128]
    const float* __restrict__ pos_s,   // [B, M, 3]
    const _Float16* __restrict__ w1t,  // [64][16]
    const _Float16* __restrict__ w2t,  // [128][64]
    float* __restrict__ x_out)         // [B, M, 128]
{
  const int blk  = blockIdx.x;
  const int b    = blk >> 11;          // / 2048
  const int m    = blk & 2047;
  const int lane = threadIdx.x;
  const int l15  = lane & 15;
  const int quad = lane >> 4;

  __shared__ int      nbr[K_];
  __shared__ _Float16 featb[K_][24];   // [32][16] + pad (bank spread)
  __shared__ _Float16 h1b[K_][72];     // [32][64] + pad, rows 144 B

  const float* pb = pos + (size_t)b * N_ * 3;
  const float* xb = x   + (size_t)b * N_ * DIN_;
  const size_t so = ((size_t)b * M_ + m) * 3;
  const float sx = pos_s[so + 0];
  const float sy = pos_s[so + 1];
  const float sz = pos_s[so + 2];
  const float R2 = (float)(0.2 * 0.2);

  // --- ball query: first K in-ball neighbors in index order (EXACT fp32) ---
  int cnt = 0;
  for (int base = 0; base < N_ && cnt < K_; base += 64) {
    int j = base + lane;
    float qx = pb[j * 3 + 0], qy = pb[j * 3 + 1], qz = pb[j * 3 + 2];
    bool win;
    {
#pragma clang fp contract(off)
      float dx = sx - qx, dy = sy - qy, dz = sz - qz;
      float d2 = (dx * dx + dy * dy) + dz * dz;
      win = d2 <= R2;
    }
    unsigned long long mk = __ballot(win);
    int rank = (int)__popcll(mk & ((1ull << lane) - 1ull));
    if (win) {
      int slot = cnt + rank;
      if (slot < K_) nbr[slot] = j;
    }
    cnt += (int)__popcll(mk);
  }
  const int valid = cnt < K_ ? cnt : K_;   // uniform across wave, >= 1
  __syncthreads();

  // --- gather -> featb (fp16): concat(x_j, pos_j - pos_s), invalid rows 0 ---
  for (int tq = lane; tq < K_ * 16; tq += 64) {
    int r = tq >> 4, i = tq & 15;
    float v = 0.f;
    if (r < valid) {
      int j = nbr[r];
      if (i < DIN_) {
        v = xb[j * DIN_ + i];
      } else {
        float c = (i == 13) ? sx : (i == 14) ? sy : sz;
        float q = pb[j * 3 + (i - 13)];
        v = q - c;
      }
    }
    featb[r][i] = (_Float16)v;
  }
  __syncthreads();

  f16x8 fz;
#pragma unroll
  for (int i = 0; i < 8; ++i) fz[i] = (_Float16)0;

  // --- A1 / B1 fragments (K=32, k>=16 zero-padded on BOTH operands) ---
  f16x8 a1[2], b1f[4];
#pragma unroll
  for (int mt = 0; mt < 2; ++mt)
    a1[mt] = (quad < 2) ? *(const f16x8*)&featb[mt * 16 + l15][quad * 8] : fz;
#pragma unroll
  for (int nt = 0; nt < 4; ++nt)
    b1f[nt] = (quad < 2) ? *(const f16x8*)&w1t[(nt * 16 + l15) * 16 + quad * 8]
                         : fz;

  // --- MLP1 MFMA + bias + relu -> h1b (fp16) ---
#pragma unroll
  for (int mt = 0; mt < 2; ++mt) {
#pragma unroll
    for (int nt = 0; nt < 4; ++nt) {
      f32x4 c = {0.f, 0.f, 0.f, 0.f};
      c = __builtin_amdgcn_mfma_f32_16x16x32_f16(a1[mt], b1f[nt], c, 0, 0, 0);
      float bb = b1[nt * 16 + l15];
#pragma unroll
      for (int r = 0; r < 4; ++r) {
        float v = c[r] + bb;
        h1b[mt * 16 + quad * 4 + r][nt * 16 + l15] =
            (_Float16)(v > 0.f ? v : 0.f);
      }
    }
  }
  __syncthreads();

  // --- A2 fragments from h1b ---
  f16x8 a2[2][2];
#pragma unroll
  for (int mt = 0; mt < 2; ++mt)
#pragma unroll
    for (int kt = 0; kt < 2; ++kt)
      a2[mt][kt] = *(const f16x8*)&h1b[mt * 16 + l15][kt * 32 + quad * 8];

  // --- MLP2 per N-tile: 4 MFMA + bias/relu/mask/max + cross-quad reduce ---
  float* o = x_out + ((size_t)b * M_ + m) * 128;
#pragma unroll
  for (int nt = 0; nt < 8; ++nt) {
    f16x8 b20 = *(const f16x8*)&w2t[(nt * 16 + l15) * 64 + 0 * 32 + quad * 8];
    f16x8 b21 = *(const f16x8*)&w2t[(nt * 16 + l15) * 64 + 1 * 32 + quad * 8];
    f32x4 c0 = {0.f, 0.f, 0.f, 0.f}, c1 = {0.f, 0.f, 0.f, 0.f};
    c0 = __builtin_amdgcn_mfma_f32_16x16x32_f16(a2[0][0], b20, c0, 0, 0, 0);
    c0 = __builtin_amdgcn_mfma_f32_16x16x32_f16(a2[0][1], b21, c0, 0, 0, 0);
    c1 = __builtin_amdgcn_mfma_f32_16x16x32_f16(a2[1][0], b20, c1, 0, 0, 0);
    c1 = __builtin_amdgcn_mfma_f32_16x16x32_f16(a2[1][1], b21, c1, 0, 0, 0);
    float bv = b2[nt * 16 + l15];
    float acc = -INFINITY;
#pragma unroll
    for (int r = 0; r < 4; ++r) {
      int row0 = quad * 4 + r;          // rows 0..15  (c0)
      int row1 = 16 + quad * 4 + r;     // rows 16..31 (c1)
      float v0 = c0[r] + bv; v0 = v0 > 0.f ? v0 : 0.f;
      float v1 = c1[r] + bv; v1 = v1 > 0.f ? v1 : 0.f;
      if (row0 < valid) acc = fmaxf(acc, v0);
      if (row1 < valid) acc = fmaxf(acc, v1);
    }
    acc = fmaxf(acc, __shfl_xor(acc, 16));
    acc = fmaxf(acc, __shfl_xor(acc, 32));
    if (quad == 0) o[nt * 16 + l15] = acc;
  }
}

// ---------------------------------------------------------------------------
extern "C" void kernel_launch(void* const* d_in, const int* in_sizes, int n_in,
                              void* d_out, int out_size, void* d_ws, size_t ws_size,
                              hipStream_t stream) {
  (void)in_sizes; (void)n_in; (void)ws_size; (void)out_size;
  const float* x   = (const float*)d_in[0];
  const float* pos = (const float*)d_in[1];
  // d_in[2] = batch (unused: always broadcast arange(B))
  const float* W1  = (const float*)d_in[3];
  const float* b1  = (const float*)d_in[4];
  const float* W2  = (const float*)d_in[5];
  const float* b2  = (const float*)d_in[6];

  float* out     = (float*)d_out;
  float* x_out   = out;                                  // [B, M, 128]
  float* pos_s   = out + (size_t)B_ * M_ * 128;          // [B, M, 3]
  float* batch_s = pos_s + (size_t)B_ * M_ * 3;          // [B, M]

  _Float16* w1t = (_Float16*)d_ws;                       // [64][16]
  _Float16* w2t = w1t + 1024;                            // [128][64]

  prep_kernel<<<36, 256, 0, stream>>>(W1, W2, w1t, w2t);
  fps_kernel<<<B_, 1024, 0, stream>>>(pos, pos_s, batch_s);
  sa_kernel<<<B_ * M_, 64, 0, stream>>>(x, pos, b1, b2, pos_s, w1t, w2t, x_out);
}

// Round 9
// 1502.773 us; speedup vs baseline: 1.3751x; 1.3751x over previous
//
#include <hip/hip_runtime.h>
#include <cstddef>

#define B_   8
#define N_   8192
#define M_   2048
#define K_   32
#define DIN_ 13

typedef _Float16 f16x8 __attribute__((ext_vector_type(8)));
typedef float    f32x4 __attribute__((ext_vector_type(4)));

// DPP-assisted reduce steps. Invalid source lanes yield identity. VALU-only.
template <int CTRL>
__device__ __forceinline__ float dppmax(float v) {
  int o = __builtin_amdgcn_update_dpp(
      (int)0xff800000, __float_as_int(v), CTRL, 0xF, 0xF, false);  // -inf
  return fmaxf(v, __int_as_float(o));
}
template <int CTRL>
__device__ __forceinline__ unsigned dppminu(unsigned v) {
  unsigned o = (unsigned)__builtin_amdgcn_update_dpp(
      (int)0xFFFFFFFF, (int)v, CTRL, 0xF, 0xF, false);  // u32 max = identity
  return v < o ? v : o;
}
__device__ __forceinline__ float wave_reduce_max(float v) {
  v = dppmax<0x111>(v); v = dppmax<0x112>(v); v = dppmax<0x114>(v);
  v = dppmax<0x118>(v); v = dppmax<0x142>(v); v = dppmax<0x143>(v);
  return __int_as_float(__builtin_amdgcn_readlane(__float_as_int(v), 63));
}
__device__ __forceinline__ unsigned wave_reduce_min_u32(unsigned v) {
  v = dppminu<0x111>(v); v = dppminu<0x112>(v); v = dppminu<0x114>(v);
  v = dppminu<0x118>(v); v = dppminu<0x142>(v); v = dppminu<0x143>(v);
  return (unsigned)__builtin_amdgcn_readlane((int)v, 63);
}

// ---------------------------------------------------------------------------
// Kernel 1 v3 (CHAMPION, round-4 measured 1377us): FPS with EXACT per-LANE
// bbox pruning. 512-voxel (3-bit/axis Morton) in-LDS counting sort -> each
// LANE owns 8 spatially tight points. Per iteration each lane computes
// LB = clampdist^2(center, lane bbox); lane's update is provably a fp no-op
// when LB*(1-1e-6) >= ltm (= max of its 8 minds). Wave processes iff ANY
// lane might change.
// Winner-select mechanism A/B/C (r4/r6/r8): lane-0 atomicMax + kslot
// broadcast read is FASTEST (1377 vs 1464 u64-DPP vs 1941 two-phase DPP) —
// the DPP alternatives build longer serial v->s dependent chains. Keep this.
// !! r7 LESSON preserved: distance expression for PROCESSED points is
//    bit-identical (subtract-form, contract(off), jnp sum order). Sort only
//    permutes ownership, never values; tie-break = smallest ORIG index via
//    per-lane tie scan + wave-min + (dist,~idx) u64 atomicMax (1/wave).
// ---------------------------------------------------------------------------
__global__ __launch_bounds__(1024, 4) void fps_kernel(
    const float* __restrict__ pos,     // [B, N, 3]
    float* __restrict__ pos_s,         // [B, M, 3]
    float* __restrict__ batch_s)       // [B, M]
{
  const int b    = blockIdx.x;
  const int t    = threadIdx.x;
  const int lane = t & 63;
  const int wid  = t >> 6;
  const float* p = pos + (size_t)b * N_ * 3;

  __shared__ float px_l[N_], py_l[N_], pz_l[N_];   // 96 KB, ORIGINAL order
  __shared__ int   r2o[N_];                        // 32 KB, rank -> orig
  __shared__ int   vbase[512];
  __shared__ int   vcur[512];
  __shared__ int   wsum[8];
  __shared__ unsigned long long kslot[3];

  for (int mm = t; mm < M_; mm += 1024)
    batch_s[b * M_ + mm] = (float)b;
  if (t < 512) vcur[t] = 0;
  if (t == 0) { kslot[0] = 0ull; kslot[1] = 0ull; kslot[2] = 0ull; }
  __syncthreads();

  // --- load points + 512-bin Morton histogram ---
  int vid[8];
#pragma unroll
  for (int i = 0; i < 8; ++i) {
    int j = t + 1024 * i;
    float x = p[j * 3 + 0], y = p[j * 3 + 1], z = p[j * 3 + 2];
    px_l[j] = x; py_l[j] = y; pz_l[j] = z;
    int ix = (int)(x * 8.f); ix = ix < 0 ? 0 : (ix > 7 ? 7 : ix);
    int iy = (int)(y * 8.f); iy = iy < 0 ? 0 : (iy > 7 ? 7 : iy);
    int iz = (int)(z * 8.f); iz = iz < 0 ? 0 : (iz > 7 ? 7 : iz);
    int v = (ix & 1) | ((iy & 1) << 1) | ((iz & 1) << 2) |
            (((ix >> 1) & 1) << 3) | (((iy >> 1) & 1) << 4) |
            (((iz >> 1) & 1) << 5) |
            ((ix >> 2) << 6) | ((iy >> 2) << 7) | ((iz >> 2) << 8);
    vid[i] = v;
    atomicAdd(&vcur[v], 1);
  }
  __syncthreads();

  // --- exclusive prefix over 512 bins (waves 0-7 scan, wave 0 combines) ---
  int h = 0, sc = 0;
  if (t < 512) {
    h = vcur[t]; sc = h;
#pragma unroll
    for (int d = 1; d < 64; d <<= 1) {
      int o = __shfl_up(sc, d);
      if (lane >= d) sc += o;
    }
    if (lane == 63) wsum[wid] = sc;
  }
  __syncthreads();
  if (t < 8) {
    int v = wsum[t]; int inc = v;
#pragma unroll
    for (int d = 1; d < 8; d <<= 1) {
      int o = __shfl_up(inc, d);
      if (t >= d) inc += o;
    }
    wsum[t] = inc - v;   // exclusive wave offset
  }
  __syncthreads();
  if (t < 512) { vbase[t] = sc - h + wsum[t >> 6]; vcur[t] = 0; }
  __syncthreads();

  // --- scatter: rank per point (within-voxel order nondeterministic; only
  //     affects ownership, never computed values) ---
#pragma unroll
  for (int i = 0; i < 8; ++i) {
    int j = t + 1024 * i;
    int r = vbase[vid[i]] + atomicAdd(&vcur[vid[i]], 1);
    r2o[r] = j;
  }
  __syncthreads();

  // --- gather: thread t owns ranks [8t,8t+8) (spatially tight) ---
  float px[8], py[8], pz[8], mind[8]; int oi[8];
#pragma unroll
  for (int i = 0; i < 8; ++i) {
    int o = r2o[t * 8 + i];
    oi[i] = o;
    px[i] = px_l[o]; py[i] = py_l[o]; pz[i] = pz_l[o];
    mind[i] = 1e10f;
  }
#pragma unroll
  for (int i = 0; i < 8; ++i) {
    asm volatile("" : "+v"(px[i]), "+v"(py[i]), "+v"(pz[i]));
  }

  // --- per-LANE bbox of the 8 owned points ---
  float bxmin = px[0], bxmax = px[0], bymin = py[0], bymax = py[0],
        bzmin = pz[0], bzmax = pz[0];
#pragma unroll
  for (int i = 1; i < 8; ++i) {
    bxmin = fminf(bxmin, px[i]); bxmax = fmaxf(bxmax, px[i]);
    bymin = fminf(bymin, py[i]); bymax = fmaxf(bymax, py[i]);
    bzmin = fminf(bzmin, pz[i]); bzmax = fmaxf(bzmax, pz[i]);
  }

  float lx = px_l[0], ly = py_l[0], lz = pz_l[0];
  if (t == 0) {
    pos_s[(size_t)b * M_ * 3 + 0] = lx;
    pos_s[(size_t)b * M_ * 3 + 1] = ly;
    pos_s[(size_t)b * M_ * 3 + 2] = lz;
  }

  float ltm = 1e10f;                  // max of MY 8 minds (exact, per-lane)
  float cwm = 0.f;                    // cached wave max (uniform)
  unsigned cmin = 0xFFFFFFFFu;        // cached wave tie-min orig idx (uniform)
  int sl = 1;   // s % 3
  int rs = 0;   // (s+2) % 3

  for (int s = 1; s < M_; ++s) {
    // per-lane conservative LB on fp-distance^2 from new center to owned pts
    float cx = fmaxf(fmaxf(bxmin - lx, lx - bxmax), 0.f);
    float cy = fmaxf(fmaxf(bymin - ly, ly - bymax), 0.f);
    float cz = fmaxf(fmaxf(bzmin - lz, lz - bzmax), 0.f);
    float LB = (cx * cx + cy * cy) + cz * cz;
    bool lp = (LB * 0.999999f < ltm);          // lane might change
    if (__ballot(lp) != 0ull) {                // wave-uniform branch
      float tmax;
      {
#pragma clang fp contract(off)
#pragma unroll
        for (int i = 0; i < 8; ++i) {
          float dx = px[i] - lx, dy = py[i] - ly, dz = pz[i] - lz;
          float d  = (dx * dx + dy * dy) + dz * dz;   // EXACT: jnp order, no fma
          mind[i]  = fminf(mind[i], d);
        }
        float m0 = fmaxf(mind[0], mind[1]), m1 = fmaxf(mind[2], mind[3]);
        float m2 = fmaxf(mind[4], mind[5]), m3 = fmaxf(mind[6], mind[7]);
        tmax = fmaxf(fmaxf(m0, m1), fmaxf(m2, m3));
      }
      ltm = tmax;
      const float wm = wave_reduce_max(tmax);
      unsigned cc = 0xFFFFFFFFu;   // smallest orig index among my ties
#pragma unroll
      for (int i = 0; i < 8; ++i) {
        unsigned cand = (mind[i] == wm) ? (unsigned)oi[i] : 0xFFFFFFFFu;
        cc = cc < cand ? cc : cand;
      }
      cmin = wave_reduce_min_u32(cc);
      cwm = wm;
    }
    // one submit per wave (fresh or cached)
    if (lane == 0) {
      unsigned long long key =
          ((unsigned long long)__float_as_uint(cwm) << 32) |
          (unsigned long long)(0xFFFFFFFFu - cmin);
      atomicMax(&kslot[sl], key);
    }
    __syncthreads();                               // the ONE barrier
    if (t == 0) kslot[rs] = 0ull;
    const unsigned long long kk = kslot[sl];
    const int wj  = (int)(0xFFFFFFFFu - (unsigned int)(kk & 0xFFFFFFFFull));
    const int wju = (int)__builtin_amdgcn_readfirstlane(wj);
    lx = px_l[wju]; ly = py_l[wju]; lz = pz_l[wju];
    if (t == 0) {
      size_t o2 = ((size_t)b * M_ + s) * 3;
      pos_s[o2 + 0] = lx; pos_s[o2 + 1] = ly; pos_s[o2 + 2] = lz;
    }
    sl = (sl == 2) ? 0 : sl + 1;
    rs = (rs == 2) ? 0 : rs + 1;
  }
}

// ---------------------------------------------------------------------------
// Prep: transpose + fp16-convert weights into workspace (once per launch).
// w1t [64 n][16 k] = W1^T ; w2t [128 n][64 k] = W2^T.
// ---------------------------------------------------------------------------
__global__ __launch_bounds__(256) void prep_kernel(
    const float* __restrict__ W1, const float* __restrict__ W2,
    _Float16* __restrict__ w1t, _Float16* __restrict__ w2t)
{
  int t = blockIdx.x * 256 + threadIdx.x;
  if (t < 8192) {
    int n = t >> 6, k = t & 63;
    w2t[t] = (_Float16)W2[k * 128 + n];
  }
  int u = t - 8192;
  if (u >= 0 && u < 1024) {
    int n = u >> 4, k = u & 15;
    w1t[u] = (_Float16)W1[k * 64 + n];
  }
}

// ---------------------------------------------------------------------------
// Kernel 2 v2: ball query (exact fp32) + gather + MFMA fp16 MLP + masked max.
// UNCHANGED (control) — see round-1 comments.
// ---------------------------------------------------------------------------
__global__ __launch_bounds__(64) void sa_kernel(
    const float* __restrict__ x,       // [B, N, 13]
    const float* __restrict__ pos,     // [B, N, 3]
    const float* __restrict__ b1,      // [64]
    const float* __restrict__ b2,      // [128]
    const float* __restrict__ pos_s,   // [B, M, 3]
    const _Float16* __restrict__ w1t,  // [64][16]
    const _Float16* __restrict__ w2t,  // [128][64]
    float* __restrict__ x_out)         // [B, M, 128]
{
  const int blk  = blockIdx.x;
  const int b    = blk >> 11;          // / 2048
  const int m    = blk & 2047;
  const int lane = threadIdx.x;
  const int l15  = lane & 15;
  const int quad = lane >> 4;

  __shared__ int      nbr[K_];
  __shared__ _Float16 featb[K_][24];   // [32][16] + pad (bank spread)
  __shared__ _Float16 h1b[K_][72];     // [32][64] + pad, rows 144 B

  const float* pb = pos + (size_t)b * N_ * 3;
  const float* xb = x   + (size_t)b * N_ * DIN_;
  const size_t so = ((size_t)b * M_ + m) * 3;
  const float sx = pos_s[so + 0];
  const float sy = pos_s[so + 1];
  const float sz = pos_s[so + 2];
  const float R2 = (float)(0.2 * 0.2);

  // --- ball query: first K in-ball neighbors in index order (EXACT fp32) ---
  int cnt = 0;
  for (int base = 0; base < N_ && cnt < K_; base += 64) {
    int j = base + lane;
    float qx = pb[j * 3 + 0], qy = pb[j * 3 + 1], qz = pb[j * 3 + 2];
    bool win;
    {
#pragma clang fp contract(off)
      float dx = sx - qx, dy = sy - qy, dz = sz - qz;
      float d2 = (dx * dx + dy * dy) + dz * dz;
      win = d2 <= R2;
    }
    unsigned long long mk = __ballot(win);
    int rank = (int)__popcll(mk & ((1ull << lane) - 1ull));
    if (win) {
      int slot = cnt + rank;
      if (slot < K_) nbr[slot] = j;
    }
    cnt += (int)__popcll(mk);
  }
  const int valid = cnt < K_ ? cnt : K_;   // uniform across wave, >= 1
  __syncthreads();

  // --- gather -> featb (fp16): concat(x_j, pos_j - pos_s), invalid rows 0 ---
  for (int tq = lane; tq < K_ * 16; tq += 64) {
    int r = tq >> 4, i = tq & 15;
    float v = 0.f;
    if (r < valid) {
      int j = nbr[r];
      if (i < DIN_) {
        v = xb[j * DIN_ + i];
      } else {
        float c = (i == 13) ? sx : (i == 14) ? sy : sz;
        float q = pb[j * 3 + (i - 13)];
        v = q - c;
      }
    }
    featb[r][i] = (_Float16)v;
  }
  __syncthreads();

  f16x8 fz;
#pragma unroll
  for (int i = 0; i < 8; ++i) fz[i] = (_Float16)0;

  // --- A1 / B1 fragments (K=32, k>=16 zero-padded on BOTH operands) ---
  f16x8 a1[2], b1f[4];
#pragma unroll
  for (int mt = 0; mt < 2; ++mt)
    a1[mt] = (quad < 2) ? *(const f16x8*)&featb[mt * 16 + l15][quad * 8] : fz;
#pragma unroll
  for (int nt = 0; nt < 4; ++nt)
    b1f[nt] = (quad < 2) ? *(const f16x8*)&w1t[(nt * 16 + l15) * 16 + quad * 8]
                         : fz;

  // --- MLP1 MFMA + bias + relu -> h1b (fp16) ---
#pragma unroll
  for (int mt = 0; mt < 2; ++mt) {
#pragma unroll
    for (int nt = 0; nt < 4; ++nt) {
      f32x4 c = {0.f, 0.f, 0.f, 0.f};
      c = __builtin_amdgcn_mfma_f32_16x16x32_f16(a1[mt], b1f[nt], c, 0, 0, 0);
      float bb = b1[nt * 16 + l15];
#pragma unroll
      for (int r = 0; r < 4; ++r) {
        float v = c[r] + bb;
        h1b[mt * 16 + quad * 4 + r][nt * 16 + l15] =
            (_Float16)(v > 0.f ? v : 0.f);
      }
    }
  }
  __syncthreads();

  // --- A2 fragments from h1b ---
  f16x8 a2[2][2];
#pragma unroll
  for (int mt = 0; mt < 2; ++mt)
#pragma unroll
    for (int kt = 0; kt < 2; ++kt)
      a2[mt][kt] = *(const f16x8*)&h1b[mt * 16 + l15][kt * 32 + quad * 8];

  // --- MLP2 per N-tile: 4 MFMA + bias/relu/mask/max + cross-quad reduce ---
  float* o = x_out + ((size_t)b * M_ + m) * 128;
#pragma unroll
  for (int nt = 0; nt < 8; ++nt) {
    f16x8 b20 = *(const f16x8*)&w2t[(nt * 16 + l15) * 64 + 0 * 32 + quad * 8];
    f16x8 b21 = *(const f16x8*)&w2t[(nt * 16 + l15) * 64 + 1 * 32 + quad * 8];
    f32x4 c0 = {0.f, 0.f, 0.f, 0.f}, c1 = {0.f, 0.f, 0.f, 0.f};
    c0 = __builtin_amdgcn_mfma_f32_16x16x32_f16(a2[0][0], b20, c0, 0, 0, 0);
    c0 = __builtin_amdgcn_mfma_f32_16x16x32_f16(a2[0][1], b21, c0, 0, 0, 0);
    c1 = __builtin_amdgcn_mfma_f32_16x16x32_f16(a2[1][0], b20, c1, 0, 0, 0);
    c1 = __builtin_amdgcn_mfma_f32_16x16x32_f16(a2[1][1], b21, c1, 0, 0, 0);
    float bv = b2[nt * 16 + l15];
    float acc = -INFINITY;
#pragma unroll
    for (int r = 0; r < 4; ++r) {
      int row0 = quad * 4 + r;          // rows 0..15  (c0)
      int row1 = 16 + quad * 4 + r;     // rows 16..31 (c1)
      float v0 = c0[r] + bv; v0 = v0 > 0.f ? v0 : 0.f;
      float v1 = c1[r] + bv; v1 = v1 > 0.f ? v1 : 0.f;
      if (row0 < valid) acc = fmaxf(acc, v0);
      if (row1 < valid) acc = fmaxf(acc, v1);
    }
    acc = fmaxf(acc, __shfl_xor(acc, 16));
    acc = fmaxf(acc, __shfl_xor(acc, 32));
    if (quad == 0) o[nt * 16 + l15] = acc;
  }
}

// ---------------------------------------------------------------------------
extern "C" void kernel_launch(void* const* d_in, const int* in_sizes, int n_in,
                              void* d_out, int out_size, void* d_ws, size_t ws_size,
                              hipStream_t stream) {
  (void)in_sizes; (void)n_in; (void)ws_size; (void)out_size;
  const float* x   = (const float*)d_in[0];
  const float* pos = (const float*)d_in[1];
  // d_in[2] = batch (unused: always broadcast arange(B))
  const float* W1  = (const float*)d_in[3];
  const float* b1  = (const float*)d_in[4];
  const float* W2  = (const float*)d_in[5];
  const float* b2  = (const float*)d_in[6];

  float* out     = (float*)d_out;
  float* x_out   = out;                                  // [B, M, 128]
  float* pos_s   = out + (size_t)B_ * M_ * 128;          // [B, M, 3]
  float* batch_s = pos_s + (size_t)B_ * M_ * 3;          // [B, M]

  _Float16* w1t = (_Float16*)d_ws;                       // [64][16]
  _Float16* w2t = w1t + 1024;                            // [128][64]

  prep_kernel<<<36, 256, 0, stream>>>(W1, W2, w1t, w2t);
  fps_kernel<<<B_, 1024, 0, stream>>>(pos, pos_s, batch_s);
  sa_kernel<<<B_ * M_, 64, 0, stream>>>(x, pos, b1, b2, pos_s, w1t, w2t, x_out);
}